// Round 12
// baseline (261.579 us; speedup 1.0000x reference)
//
#include <hip/hip_runtime.h>

typedef unsigned short ushort;
typedef short bf16x8 __attribute__((ext_vector_type(8)));   // 8 bf16 in 4 VGPRs
typedef float f32x4 __attribute__((ext_vector_type(4)));

static __device__ __forceinline__ ushort f2b(float f) {
  unsigned u = __builtin_bit_cast(unsigned, f);
  u = (u + 0x7fffu + ((u >> 16) & 1u)) >> 16;
  return (ushort)u;
}
static __device__ __forceinline__ float b2f(ushort b) {
  return __builtin_bit_cast(float, (unsigned)b << 16);
}

// MEASUREMENT ROUND: every kernel repeats its (idempotent) work 4x so our
// dispatches exceed the ~43us harness-fill floor and surface in rocprof
// top-5 with full counters. dur_us ~= overhead + 4 * kernel_sum.
#define REP 4

// ---------------------------------------------------------------------------
// prep: LDS-tiled 32x32 transpose for all five fp32->bf16 transposes.
// ---------------------------------------------------------------------------
__global__ __launch_bounds__(256) void prep_kernel(
    const float* __restrict__ x,
    const float* __restrict__ w_qkv, const float* __restrict__ w_proj,
    const float* __restrict__ w_fc1, const float* __restrict__ w_fc2,
    ushort* __restrict__ xb, ushort* __restrict__ wqkvT,
    ushort* __restrict__ wprojT, ushort* __restrict__ wfc1T,
    ushort* __restrict__ wfc2T)
{
  __shared__ float tile[32][33];
  int t = blockIdx.x;
  const float* src; ushort* dst; int R, Nc, r0, c0;
  if (t < 2048)              { src = x;      dst = xb;     R = 256; Nc = 8192; r0 = (t >> 8) * 32; c0 = (t & 255) * 32; }
  else if ((t -= 2048) < 192){ src = w_qkv;  dst = wqkvT;  R = 256; Nc = 768;  r0 = (t / 24) * 32; c0 = (t % 24) * 32; }
  else if ((t -= 192) < 64)  { src = w_proj; dst = wprojT; R = 256; Nc = 256;  r0 = (t / 8) * 32;  c0 = (t % 8) * 32; }
  else if ((t -= 64) < 128)  { src = w_fc1;  dst = wfc1T;  R = 256; Nc = 512;  r0 = (t / 16) * 32; c0 = (t % 16) * 32; }
  else           { t -= 128;   src = w_fc2;  dst = wfc2T;  R = 512; Nc = 256;  r0 = (t / 8) * 32;  c0 = (t % 8) * 32; }

  const int tx = threadIdx.x & 31, ty = threadIdx.x >> 5;
  for (int rep = 0; rep < REP; rep++) {
    #pragma unroll
    for (int i = 0; i < 4; i++)
      tile[ty + i * 8][tx] = src[(size_t)(r0 + ty + i * 8) * Nc + c0 + tx];
    __syncthreads();
    #pragma unroll
    for (int i = 0; i < 4; i++)
      dst[(size_t)(c0 + ty + i * 8) * R + r0 + tx] = f2b(tile[tx][ty + i * 8]);
    __syncthreads();   // WAR protection across reps
  }
}

// ---------------------------------------------------------------------------
// MFMA bf16 GEMM, 64x64 tile, 4 waves, BK=128 (round-11 engine), rep-looped.
// ---------------------------------------------------------------------------
template<int EPI, int KD>
__global__ __launch_bounds__(256) void gemm_mfma(
    const ushort* __restrict__ A, const ushort* __restrict__ Bt,
    const float* __restrict__ bias, const float* __restrict__ R,
    const ushort* __restrict__ RS,
    void* __restrict__ C0, void* __restrict__ C1,
    int M, int N)
{
  constexpr int LDW = 136;                      // padded row stride (ushorts)
  __shared__ __attribute__((aligned(16))) ushort As[64 * LDW];
  __shared__ __attribute__((aligned(16))) ushort Bs[64 * LDW];

  const int bm = blockIdx.y * 64;
  const int bn = blockIdx.x * 64;
  const int t  = threadIdx.x;
  const int w    = t >> 6;
  const int lane = t & 63;
  const int wm = (w & 1) * 32;
  const int wn = (w >> 1) * 32;
  const int lm = lane & 15;
  const int kq = lane >> 4;                     // 0..3

  for (int rep = 0; rep < REP; rep++) {
    f32x4 acc[2][2] = {};

    #pragma unroll
    for (int k0 = 0; k0 < KD; k0 += 128) {
      uint4 ra[4], rb[4];
      #pragma unroll
      for (int s = 0; s < 4; s++) {
        const int L = t + 256 * s;
        const int r = L >> 4, c = L & 15;
        ra[s] = *(const uint4*)(A  + (size_t)(bm + r) * KD + k0 + c * 8);
        rb[s] = *(const uint4*)(Bt + (size_t)(bn + r) * KD + k0 + c * 8);
      }
      #pragma unroll
      for (int s = 0; s < 4; s++) {
        const int L = t + 256 * s;
        const int r = L >> 4, c = L & 15;
        *(uint4*)(&As[r * LDW + c * 8]) = ra[s];
        *(uint4*)(&Bs[r * LDW + c * 8]) = rb[s];
      }
      __syncthreads();

      #pragma unroll
      for (int ks = 0; ks < 4; ks++) {
        const int ko = ks * 32 + kq * 8;
        bf16x8 a0 = *(const bf16x8*)(&As[(wm + lm)      * LDW + ko]);
        bf16x8 a1 = *(const bf16x8*)(&As[(wm + 16 + lm) * LDW + ko]);
        bf16x8 b0 = *(const bf16x8*)(&Bs[(wn + lm)      * LDW + ko]);
        bf16x8 b1 = *(const bf16x8*)(&Bs[(wn + 16 + lm) * LDW + ko]);
        acc[0][0] = __builtin_amdgcn_mfma_f32_16x16x32_bf16(a0, b0, acc[0][0], 0, 0, 0);
        acc[0][1] = __builtin_amdgcn_mfma_f32_16x16x32_bf16(a0, b1, acc[0][1], 0, 0, 0);
        acc[1][0] = __builtin_amdgcn_mfma_f32_16x16x32_bf16(a1, b0, acc[1][0], 0, 0, 0);
        acc[1][1] = __builtin_amdgcn_mfma_f32_16x16x32_bf16(a1, b1, acc[1][1], 0, 0, 0);
      }
      __syncthreads();
    }

    #pragma unroll
    for (int ti = 0; ti < 2; ti++) {
      #pragma unroll
      for (int tj = 0; tj < 2; tj++) {
        const int n  = bn + wn + tj * 16 + lm;
        const int m0 = bm + wm + ti * 16 + kq * 4;
        if (EPI == 3) {
          float4 v;
          float* vp = &v.x;
          #pragma unroll
          for (int r = 0; r < 4; r++)
            vp[r] = acc[ti][tj][r] + bias[n] + b2f(RS[(size_t)(m0 + r) * 256 + n]);
          *(float4*)((float*)C0 + (size_t)n * M + m0) = v;
        } else if (EPI == 0) {
          if (n < 512) {
            #pragma unroll
            for (int r = 0; r < 4; r++)
              ((ushort*)C0)[(size_t)(m0 + r) * N + n] = f2b(acc[ti][tj][r] + bias[n]);
          } else {
            ushort4 st;
            st.x = f2b(acc[ti][tj][0] + bias[n]);
            st.y = f2b(acc[ti][tj][1] + bias[n]);
            st.z = f2b(acc[ti][tj][2] + bias[n]);
            st.w = f2b(acc[ti][tj][3] + bias[n]);
            *(ushort4*)((ushort*)C1 + (size_t)(n - 512) * 8192 + m0) = st;
          }
        } else {
          #pragma unroll
          for (int r = 0; r < 4; r++) {
            const int m = m0 + r;
            float v = acc[ti][tj][r] + bias[n];
            if (EPI == 1) {
              v += R[(size_t)n * M + m];
              ((ushort*)C0)[(size_t)m * 256 + n] = f2b(v);
            } else {  // EPI 2
              v = 0.5f * v * (1.0f + erff(v * 0.70710678118f));
              ((ushort*)C0)[(size_t)m * N + n] = f2b(v);
            }
          }
        }
      }
    }
  }
}

// ---------------------------------------------------------------------------
// MFMA neighborhood attention, barrier-free, rep-looped.
// ---------------------------------------------------------------------------
__global__ __launch_bounds__(256) void natt_mfma(
    const ushort* __restrict__ qkv, const ushort* __restrict__ vT,
    const float* __restrict__ rpb, ushort* __restrict__ att)
{
  __shared__ __attribute__((aligned(16))) ushort Plds[4][7][16][40];
  __shared__ float Rlds[4][176];

  const int w    = threadIdx.x >> 6;
  const int lane = threadIdx.x & 63;
  const int l  = lane & 15;
  const int q  = lane >> 4;
  const int tile = blockIdx.x;            // 0..511
  const int n    = blockIdx.y * 4 + w;    // head 0..7
  const int ph  = tile >> 3;
  const int pw0 = (tile & 7) << 4;
  const int p0  = ph * 128 + pw0;

  int sh = ph - 3;  sh = sh < 0 ? 0 : (sh > 57 ? 57 : sh);
  int sb = pw0 - 3; sb = sb < 0 ? 0 : sb;
  const int sba = sb & ~7;                // 16B-aligned span base; span <= 29 cols

  for (int rep = 0; rep < REP; rep++) {
    const float L2E = 1.44269504f;
    for (int idx = lane; idx < 169; idx += 64)
      Rlds[w][idx] = rpb[n * 169 + idx] * L2E;

    bf16x8 qf = *(const bf16x8*)(qkv + (size_t)(p0 + l) * 768 + n * 32 + q * 8);

    f32x4 s[7][2] = {};
    #pragma unroll
    for (int i = 0; i < 7; i++) {
      const int rowp = (sh + i) * 128;
      #pragma unroll
      for (int h = 0; h < 2; h++) {
        int jc = sba + h * 16 + l;
        jc = jc > 127 ? 127 : jc;           // clamp addr; junk masked later
        bf16x8 kf = *(const bf16x8*)(qkv + (size_t)(rowp + jc) * 768 + 256 + n * 32 + q * 8);
        s[i][h] = __builtin_amdgcn_mfma_f32_16x16x32_bf16(qf, kf, s[i][h], 0, 0, 0);
      }
    }

    const float KSC = 0.17677669529663689f * 1.44269504f;  // hd^-0.5 * log2(e)
    const int relh0 = sh - ph + 6;          // 0..6
    float rsum[4] = {0.f, 0.f, 0.f, 0.f};
    #pragma unroll
    for (int r = 0; r < 4; r++) {
      const int pw = pw0 + q * 4 + r;
      int sw = pw - 3; sw = sw < 0 ? 0 : (sw > 121 ? 121 : sw);
      #pragma unroll
      for (int h = 0; h < 2; h++) {
        const int jc = sba + h * 16 + l;
        const bool valid = (unsigned)(jc - sw) <= 6u;
        int relw = jc - pw + 6;
        relw = relw < 0 ? 0 : (relw > 12 ? 12 : relw);
        #pragma unroll
        for (int i = 0; i < 7; i++) {
          float b = Rlds[w][(relh0 + i) * 13 + relw];
          float v = s[i][h][r] * KSC + b;
          v = valid ? v : -1e30f;
          float e = exp2f(v);
          s[i][h][r] = e;
          rsum[r] += e;
        }
      }
    }
    #pragma unroll
    for (int r = 0; r < 4; r++) {
      rsum[r] += __shfl_xor(rsum[r], 1);
      rsum[r] += __shfl_xor(rsum[r], 2);
      rsum[r] += __shfl_xor(rsum[r], 4);
      rsum[r] += __shfl_xor(rsum[r], 8);
    }

    #pragma unroll
    for (int i = 0; i < 7; i++)
      #pragma unroll
      for (int h = 0; h < 2; h++)
        #pragma unroll
        for (int r = 0; r < 4; r++)
          Plds[w][i][q * 4 + r][h * 16 + l] = f2b(s[i][h][r]);

    f32x4 o[2] = {};
    #pragma unroll
    for (int i = 0; i < 7; i++) {
      bf16x8 pf = *(const bf16x8*)(&Plds[w][i][l][q * 8]);
      const int rowp = (sh + i) * 128;
      #pragma unroll
      for (int dh = 0; dh < 2; dh++) {
        bf16x8 vf = *(const bf16x8*)(vT + (size_t)(n * 32 + dh * 16 + l) * 8192
                                        + rowp + sba + q * 8);
        o[dh] = __builtin_amdgcn_mfma_f32_16x16x32_bf16(pf, vf, o[dh], 0, 0, 0);
      }
    }

    #pragma unroll
    for (int r = 0; r < 4; r++) {
      const float inv = 1.0f / rsum[r];
      #pragma unroll
      for (int dh = 0; dh < 2; dh++)
        att[(size_t)(p0 + q * 4 + r) * 256 + n * 32 + dh * 16 + l] = f2b(o[dh][r] * inv);
    }
  }
}

// ---------------------------------------------------------------------------
extern "C" void kernel_launch(void* const* d_in, const int* in_sizes, int n_in,
                              void* d_out, int out_size, void* d_ws, size_t ws_size,
                              hipStream_t stream)
{
  const float* x      = (const float*)d_in[0];
  const float* w_qkv  = (const float*)d_in[1];
  const float* b_qkv  = (const float*)d_in[2];
  const float* rpb    = (const float*)d_in[3];
  const float* w_proj = (const float*)d_in[4];
  const float* b_proj = (const float*)d_in[5];
  const float* w_fc1  = (const float*)d_in[6];
  const float* b_fc1  = (const float*)d_in[7];
  const float* w_fc2  = (const float*)d_in[8];
  const float* b_fc2  = (const float*)d_in[9];
  float* out = (float*)d_out;

  const int M = 8192;
  char* ws = (char*)d_ws;
  ushort* xb     = (ushort*)(ws);               //  4,194,304 B (reused as att)
  ushort* qkv    = (ushort*)(ws + 4194304);     // 12,582,912 B (reused as h)
  ushort* x1b    = (ushort*)(ws + 16777216);    //  4,194,304 B
  ushort* wqkvT  = (ushort*)(ws + 20971520);    //    393,216 B
  ushort* wprojT = (ushort*)(ws + 21364736);    //    131,072 B
  ushort* wfc1T  = (ushort*)(ws + 21495808);    //    262,144 B
  ushort* wfc2T  = (ushort*)(ws + 21757952);    //    262,144 B
  ushort* vT     = (ushort*)(ws + 22020096);    //  4,194,304 B + 64K pad
  ushort* att = xb;                             // xb dead after qkv GEMM
  ushort* h   = qkv;                            // qkv dead after natt

  dim3 blk(256);

  prep_kernel<<<dim3(2560), blk, 0, stream>>>(
      x, w_qkv, w_proj, w_fc1, w_fc2, xb, wqkvT, wprojT, wfc1T, wfc2T);

  // qkv = xb @ wqkvT^T + b_qkv  -> q,k rows + transposed vT
  gemm_mfma<0, 256><<<dim3(768 / 64, M / 64), blk, 0, stream>>>(
      xb, wqkvT, b_qkv, nullptr, nullptr, qkv, vT, M, 768);

  natt_mfma<<<dim3(512, 2), blk, 0, stream>>>(qkv, vT, rpb, att);

  // x1b = bf16(att @ wprojT^T + b_proj + x(chw))
  gemm_mfma<1, 256><<<dim3(256 / 64, M / 64), blk, 0, stream>>>(
      att, wprojT, b_proj, x, nullptr, x1b, nullptr, M, 256);

  // h = gelu(x1b @ wfc1T^T + b_fc1) -> bf16
  gemm_mfma<2, 256><<<dim3(512 / 64, M / 64), blk, 0, stream>>>(
      x1b, wfc1T, b_fc1, nullptr, nullptr, h, nullptr, M, 512);

  // out(chw) = h @ wfc2T^T + b_fc2 + b2f(x1b)
  gemm_mfma<3, 512><<<dim3(256 / 64, M / 64), blk, 0, stream>>>(
      h, wfc2T, b_fc2, nullptr, x1b, out, nullptr, M, 256);
}

// Round 13
// 132.770 us; speedup vs baseline: 1.9702x; 1.9702x over previous
//
#include <hip/hip_runtime.h>

typedef unsigned short ushort;
typedef short bf16x8 __attribute__((ext_vector_type(8)));   // 8 bf16 in 4 VGPRs
typedef float f32x4 __attribute__((ext_vector_type(4)));

static __device__ __forceinline__ ushort f2b(float f) {
  unsigned u = __builtin_bit_cast(unsigned, f);
  u = (u + 0x7fffu + ((u >> 16) & 1u)) >> 16;
  return (ushort)u;
}
static __device__ __forceinline__ float b2f(ushort b) {
  return __builtin_bit_cast(float, (unsigned)b << 16);
}

// ---------------------------------------------------------------------------
// prep: LDS-tiled 32x32 transpose for all five fp32->bf16 transposes.
// ---------------------------------------------------------------------------
__global__ __launch_bounds__(256) void prep_kernel(
    const float* __restrict__ x,
    const float* __restrict__ w_qkv, const float* __restrict__ w_proj,
    const float* __restrict__ w_fc1, const float* __restrict__ w_fc2,
    ushort* __restrict__ xb, ushort* __restrict__ wqkvT,
    ushort* __restrict__ wprojT, ushort* __restrict__ wfc1T,
    ushort* __restrict__ wfc2T)
{
  __shared__ float tile[32][33];
  int t = blockIdx.x;
  const float* src; ushort* dst; int R, Nc, r0, c0;
  if (t < 2048)              { src = x;      dst = xb;     R = 256; Nc = 8192; r0 = (t >> 8) * 32; c0 = (t & 255) * 32; }
  else if ((t -= 2048) < 192){ src = w_qkv;  dst = wqkvT;  R = 256; Nc = 768;  r0 = (t / 24) * 32; c0 = (t % 24) * 32; }
  else if ((t -= 192) < 64)  { src = w_proj; dst = wprojT; R = 256; Nc = 256;  r0 = (t / 8) * 32;  c0 = (t % 8) * 32; }
  else if ((t -= 64) < 128)  { src = w_fc1;  dst = wfc1T;  R = 256; Nc = 512;  r0 = (t / 16) * 32; c0 = (t % 16) * 32; }
  else           { t -= 128;   src = w_fc2;  dst = wfc2T;  R = 512; Nc = 256;  r0 = (t / 8) * 32;  c0 = (t % 8) * 32; }

  const int tx = threadIdx.x & 31, ty = threadIdx.x >> 5;
  #pragma unroll
  for (int i = 0; i < 4; i++)
    tile[ty + i * 8][tx] = src[(size_t)(r0 + ty + i * 8) * Nc + c0 + tx];
  __syncthreads();
  #pragma unroll
  for (int i = 0; i < 4; i++)
    dst[(size_t)(c0 + ty + i * 8) * R + r0 + tx] = f2b(tile[tx][ty + i * 8]);
}

// ---------------------------------------------------------------------------
// MFMA bf16 GEMM, 64x64 tile, 4 waves, BK=128 (round-11 engine).
// EPI 0: qkv -> q,k rows to C0[m*N+n]; v (n>=512) -> C1 vT[(n-512)*8192+m]
// EPI 1: proj  -> v += x_chw[n*M+m] (fp32 R); x1b[m*256+n] = bf16(v)
// EPI 2: fc1   -> gelu(v) -> bf16 C0[m*N+n]
// EPI 3: fc2   -> v += b2f(RS[m*256+n]); out[n*M+m]=v (f32 chw, float4)
// ---------------------------------------------------------------------------
template<int EPI, int KD>
__global__ __launch_bounds__(256) void gemm_mfma(
    const ushort* __restrict__ A, const ushort* __restrict__ Bt,
    const float* __restrict__ bias, const float* __restrict__ R,
    const ushort* __restrict__ RS,
    void* __restrict__ C0, void* __restrict__ C1,
    int M, int N)
{
  constexpr int LDW = 136;                      // padded row stride (ushorts)
  __shared__ __attribute__((aligned(16))) ushort As[64 * LDW];
  __shared__ __attribute__((aligned(16))) ushort Bs[64 * LDW];

  const int bm = blockIdx.y * 64;
  const int bn = blockIdx.x * 64;
  const int t  = threadIdx.x;
  const int w    = t >> 6;
  const int lane = t & 63;
  const int wm = (w & 1) * 32;
  const int wn = (w >> 1) * 32;
  const int lm = lane & 15;
  const int kq = lane >> 4;                     // 0..3

  f32x4 acc[2][2] = {};

  #pragma unroll
  for (int k0 = 0; k0 < KD; k0 += 128) {
    uint4 ra[4], rb[4];
    #pragma unroll
    for (int s = 0; s < 4; s++) {
      const int L = t + 256 * s;
      const int r = L >> 4, c = L & 15;
      ra[s] = *(const uint4*)(A  + (size_t)(bm + r) * KD + k0 + c * 8);
      rb[s] = *(const uint4*)(Bt + (size_t)(bn + r) * KD + k0 + c * 8);
    }
    #pragma unroll
    for (int s = 0; s < 4; s++) {
      const int L = t + 256 * s;
      const int r = L >> 4, c = L & 15;
      *(uint4*)(&As[r * LDW + c * 8]) = ra[s];
      *(uint4*)(&Bs[r * LDW + c * 8]) = rb[s];
    }
    __syncthreads();

    #pragma unroll
    for (int ks = 0; ks < 4; ks++) {
      const int ko = ks * 32 + kq * 8;
      bf16x8 a0 = *(const bf16x8*)(&As[(wm + lm)      * LDW + ko]);
      bf16x8 a1 = *(const bf16x8*)(&As[(wm + 16 + lm) * LDW + ko]);
      bf16x8 b0 = *(const bf16x8*)(&Bs[(wn + lm)      * LDW + ko]);
      bf16x8 b1 = *(const bf16x8*)(&Bs[(wn + 16 + lm) * LDW + ko]);
      acc[0][0] = __builtin_amdgcn_mfma_f32_16x16x32_bf16(a0, b0, acc[0][0], 0, 0, 0);
      acc[0][1] = __builtin_amdgcn_mfma_f32_16x16x32_bf16(a0, b1, acc[0][1], 0, 0, 0);
      acc[1][0] = __builtin_amdgcn_mfma_f32_16x16x32_bf16(a1, b0, acc[1][0], 0, 0, 0);
      acc[1][1] = __builtin_amdgcn_mfma_f32_16x16x32_bf16(a1, b1, acc[1][1], 0, 0, 0);
    }
    __syncthreads();
  }

  #pragma unroll
  for (int ti = 0; ti < 2; ti++) {
    #pragma unroll
    for (int tj = 0; tj < 2; tj++) {
      const int n  = bn + wn + tj * 16 + lm;
      const int m0 = bm + wm + ti * 16 + kq * 4;
      if (EPI == 3) {
        float4 v;
        float* vp = &v.x;
        #pragma unroll
        for (int r = 0; r < 4; r++)
          vp[r] = acc[ti][tj][r] + bias[n] + b2f(RS[(size_t)(m0 + r) * 256 + n]);
        *(float4*)((float*)C0 + (size_t)n * M + m0) = v;
      } else if (EPI == 0) {
        if (n < 512) {
          #pragma unroll
          for (int r = 0; r < 4; r++)
            ((ushort*)C0)[(size_t)(m0 + r) * N + n] = f2b(acc[ti][tj][r] + bias[n]);
        } else {
          ushort4 st;
          st.x = f2b(acc[ti][tj][0] + bias[n]);
          st.y = f2b(acc[ti][tj][1] + bias[n]);
          st.z = f2b(acc[ti][tj][2] + bias[n]);
          st.w = f2b(acc[ti][tj][3] + bias[n]);
          *(ushort4*)((ushort*)C1 + (size_t)(n - 512) * 8192 + m0) = st;
        }
      } else {
        #pragma unroll
        for (int r = 0; r < 4; r++) {
          const int m = m0 + r;
          float v = acc[ti][tj][r] + bias[n];
          if (EPI == 1) {
            v += R[(size_t)n * M + m];
            ((ushort*)C0)[(size_t)m * 256 + n] = f2b(v);
          } else {  // EPI 2
            v = 0.5f * v * (1.0f + erff(v * 0.70710678118f));
            ((ushort*)C0)[(size_t)m * N + n] = f2b(v);
          }
        }
      }
    }
  }
}

// ---------------------------------------------------------------------------
// MFMA neighborhood attention v3: barrier-free, h-split to halve score
// register pressure (QK(h) -> softmax(h) with fused P-write -> next h);
// __launch_bounds__(256,4) pins VGPR <= 128 -> 4 blocks/CU (was 132 VGPR,
// just over the 128 occupancy cliff -> 3 blocks/CU, Occupancy 10.6%).
// ---------------------------------------------------------------------------
__global__ __launch_bounds__(256, 4) void natt_mfma(
    const ushort* __restrict__ qkv, const ushort* __restrict__ vT,
    const float* __restrict__ rpb, ushort* __restrict__ att)
{
  __shared__ __attribute__((aligned(16))) ushort Plds[4][7][16][40];
  __shared__ float Rlds[4][176];

  const int w    = threadIdx.x >> 6;
  const int lane = threadIdx.x & 63;
  const int l  = lane & 15;
  const int q  = lane >> 4;
  const int tile = blockIdx.x;            // 0..511
  const int n    = blockIdx.y * 4 + w;    // head 0..7
  const int ph  = tile >> 3;
  const int pw0 = (tile & 7) << 4;
  const int p0  = ph * 128 + pw0;

  int sh = ph - 3;  sh = sh < 0 ? 0 : (sh > 57 ? 57 : sh);
  int sb = pw0 - 3; sb = sb < 0 ? 0 : sb;
  const int sba = sb & ~7;                // 16B-aligned span base; span <= 29 cols

  const float L2E = 1.44269504f;
  for (int idx = lane; idx < 169; idx += 64)
    Rlds[w][idx] = rpb[n * 169 + idx] * L2E;

  bf16x8 qf = *(const bf16x8*)(qkv + (size_t)(p0 + l) * 768 + n * 32 + q * 8);

  const float KSC = 0.17677669529663689f * 1.44269504f;  // hd^-0.5 * log2(e)
  const int relh0 = sh - ph + 6;          // 0..6
  float rsum[4] = {0.f, 0.f, 0.f, 0.f};

  #pragma unroll
  for (int h = 0; h < 2; h++) {
    // QK^T for this column-half: 7 MFMAs, 28 acc VGPRs live
    f32x4 s[7] = {};
    #pragma unroll
    for (int i = 0; i < 7; i++) {
      const int rowp = (sh + i) * 128;
      int jc = sba + h * 16 + l;
      jc = jc > 127 ? 127 : jc;           // clamp addr; junk masked below
      bf16x8 kf = *(const bf16x8*)(qkv + (size_t)(rowp + jc) * 768 + 256 + n * 32 + q * 8);
      s[i] = __builtin_amdgcn_mfma_f32_16x16x32_bf16(qf, kf, s[i], 0, 0, 0);
    }
    // softmax for this half, P-write fused (scores die right after exp2)
    #pragma unroll
    for (int r = 0; r < 4; r++) {
      const int pw = pw0 + q * 4 + r;
      int sw = pw - 3; sw = sw < 0 ? 0 : (sw > 121 ? 121 : sw);
      const int jc = sba + h * 16 + l;
      const bool valid = (unsigned)(jc - sw) <= 6u;
      int relw = jc - pw + 6;
      relw = relw < 0 ? 0 : (relw > 12 ? 12 : relw);
      #pragma unroll
      for (int i = 0; i < 7; i++) {
        float b = Rlds[w][(relh0 + i) * 13 + relw];
        float v = s[i][r] * KSC + b;
        v = valid ? v : -1e30f;
        float e = exp2f(v);
        rsum[r] += e;
        Plds[w][i][q * 4 + r][h * 16 + l] = f2b(e);
      }
    }
  }

  #pragma unroll
  for (int r = 0; r < 4; r++) {
    rsum[r] += __shfl_xor(rsum[r], 1);
    rsum[r] += __shfl_xor(rsum[r], 2);
    rsum[r] += __shfl_xor(rsum[r], 4);
    rsum[r] += __shfl_xor(rsum[r], 8);
  }

  f32x4 o[2] = {};
  #pragma unroll
  for (int i = 0; i < 7; i++) {
    bf16x8 pf = *(const bf16x8*)(&Plds[w][i][l][q * 8]);
    const int rowp = (sh + i) * 128;
    #pragma unroll
    for (int dh = 0; dh < 2; dh++) {
      bf16x8 vf = *(const bf16x8*)(vT + (size_t)(n * 32 + dh * 16 + l) * 8192
                                      + rowp + sba + q * 8);
      o[dh] = __builtin_amdgcn_mfma_f32_16x16x32_bf16(pf, vf, o[dh], 0, 0, 0);
    }
  }

  #pragma unroll
  for (int r = 0; r < 4; r++) {
    const float inv = 1.0f / rsum[r];
    #pragma unroll
    for (int dh = 0; dh < 2; dh++)
      att[(size_t)(p0 + q * 4 + r) * 256 + n * 32 + dh * 16 + l] = f2b(o[dh][r] * inv);
  }
}

// ---------------------------------------------------------------------------
extern "C" void kernel_launch(void* const* d_in, const int* in_sizes, int n_in,
                              void* d_out, int out_size, void* d_ws, size_t ws_size,
                              hipStream_t stream)
{
  const float* x      = (const float*)d_in[0];
  const float* w_qkv  = (const float*)d_in[1];
  const float* b_qkv  = (const float*)d_in[2];
  const float* rpb    = (const float*)d_in[3];
  const float* w_proj = (const float*)d_in[4];
  const float* b_proj = (const float*)d_in[5];
  const float* w_fc1  = (const float*)d_in[6];
  const float* b_fc1  = (const float*)d_in[7];
  const float* w_fc2  = (const float*)d_in[8];
  const float* b_fc2  = (const float*)d_in[9];
  float* out = (float*)d_out;

  const int M = 8192;
  char* ws = (char*)d_ws;
  ushort* xb     = (ushort*)(ws);               //  4,194,304 B (reused as att)
  ushort* qkv    = (ushort*)(ws + 4194304);     // 12,582,912 B (reused as h)
  ushort* x1b    = (ushort*)(ws + 16777216);    //  4,194,304 B
  ushort* wqkvT  = (ushort*)(ws + 20971520);    //    393,216 B
  ushort* wprojT = (ushort*)(ws + 21364736);    //    131,072 B
  ushort* wfc1T  = (ushort*)(ws + 21495808);    //    262,144 B
  ushort* wfc2T  = (ushort*)(ws + 21757952);    //    262,144 B
  ushort* vT     = (ushort*)(ws + 22020096);    //  4,194,304 B + 64K pad
  ushort* att = xb;                             // xb dead after qkv GEMM
  ushort* h   = qkv;                            // qkv dead after natt

  dim3 blk(256);

  prep_kernel<<<dim3(2560), blk, 0, stream>>>(
      x, w_qkv, w_proj, w_fc1, w_fc2, xb, wqkvT, wprojT, wfc1T, wfc2T);

  // qkv = xb @ wqkvT^T + b_qkv  -> q,k rows + transposed vT
  gemm_mfma<0, 256><<<dim3(768 / 64, M / 64), blk, 0, stream>>>(
      xb, wqkvT, b_qkv, nullptr, nullptr, qkv, vT, M, 768);

  natt_mfma<<<dim3(512, 2), blk, 0, stream>>>(qkv, vT, rpb, att);

  // x1b = bf16(att @ wprojT^T + b_proj + x(chw))
  gemm_mfma<1, 256><<<dim3(256 / 64, M / 64), blk, 0, stream>>>(
      att, wprojT, b_proj, x, nullptr, x1b, nullptr, M, 256);

  // h = gelu(x1b @ wfc1T^T + b_fc1) -> bf16
  gemm_mfma<2, 256><<<dim3(512 / 64, M / 64), blk, 0, stream>>>(
      x1b, wfc1T, b_fc1, nullptr, nullptr, h, nullptr, M, 512);

  // out(chw) = h @ wfc2T^T + b_fc2 + b2f(x1b)
  gemm_mfma<3, 512><<<dim3(256 / 64, M / 64), blk, 0, stream>>>(
      h, wfc2T, b_fc2, nullptr, x1b, out, nullptr, M, 256);
}